// Round 7
// baseline (555.276 us; speedup 1.0000x reference)
//
#include <hip/hip_runtime.h>
#include <hip/hip_bf16.h>
#include <math.h>

// GNO collapsed: h = lift(x); per layer h = gelu(h@weff + beff) where
//   weff = Wb + c0*Wq@M, beff = bb + c0*bq@M,
//   M = Wk^T G Wv + (Wk^T s) bv^T + bk (s^T Wv) + N bk bv^T, G = h^T h, s = h^T 1.
// Round 7: persistent kernel via REGULAR launch + manual grid barrier
// (round 6's hipLaunchCooperativeKernel silently failed; return code unchecked).
// LDS cut to ~30 KB (sequential G/Wk/Wq staging) so 256 blocks are trivially
// co-resident (>=5 blocks/CU capacity, 1 needed). h stays in LDS all 4 layers.

#define NLAYER 4
#define NB 2
#define NN 4096
#define DD 64
#define RPB 32              // rows per block (8192 rows / 256 blocks)
#define NT 256
#define NBLK 256
#define PPB 128             // G-partial slots per batch
#define C0F (1.0f/32768.0f) // (1/sqrt(64))/4096
#define SHP 68              // padded LDS stride
#define SCRN 5320           // scratch floats (see layout in setup_body)

typedef __hip_bfloat16 bf16;

__device__ __forceinline__ float b2f(const bf16 v) { return __bfloat162float(v); }

template <typename T> struct Acc;
template <> struct Acc<float> {
    static __device__ __forceinline__ float ld(const void* p, int i) { return ((const float*)p)[i]; }
    static __device__ __forceinline__ void st(void* p, int i, float v) { ((float*)p)[i] = v; }
};
template <> struct Acc<bf16> {
    static __device__ __forceinline__ float ld(const void* p, int i) { return b2f(((const bf16*)p)[i]); }
    static __device__ __forceinline__ void st(void* p, int i, float v) { ((bf16*)p)[i] = __float2bfloat16(v); }
};

__device__ __forceinline__ float gelu_exact(float x) {
    return 0.5f * x * (1.0f + erff(x * 0.70710678118654752f));
}

// Monotonic grid barrier: all NBLK blocks co-resident (30 KB LDS -> >=5/CU cap).
// Release: __threadfence (agent scope, L2 writeback) + release atomic.
// Acquire: acquire spin load + __threadfence (L1/L2 inval). Bounded spin guard
// so a residency failure shows as wrong output, not a hang.
__device__ __forceinline__ void grid_barrier(unsigned* bar, int t) {
    __syncthreads();                 // block work done (drains vmem via waitcnt)
    if (t == 0) {
        __threadfence();
        unsigned arrive = __hip_atomic_fetch_add(bar, 1u, __ATOMIC_RELEASE,
                                                 __HIP_MEMORY_SCOPE_AGENT);
        unsigned target = (arrive / (unsigned)NBLK + 1u) * (unsigned)NBLK;
        int guard = 0;
        while (__hip_atomic_load(bar, __ATOMIC_ACQUIRE, __HIP_MEMORY_SCOPE_AGENT) < target
               && ++guard < (1 << 20))
            __builtin_amdgcn_s_sleep(2);
        __threadfence();
    }
    __syncthreads();
}

// G-partial (4x4 tile/thread over RPB LDS rows) + s-partial, plain stores.
__device__ __forceinline__ void accG_part(const float (*sH)[SHP], int t,
                                          float* __restrict__ Gp, float* __restrict__ sp)
{
    const int tr4 = (t >> 4) << 2, tc4 = (t & 15) << 2;
    float m[4][4];
    #pragma unroll
    for (int a = 0; a < 4; a++)
        #pragma unroll
        for (int b = 0; b < 4; b++) m[a][b] = 0.f;
    #pragma unroll 8
    for (int n = 0; n < RPB; n++) {
        float4 he = *(const float4*)&sH[n][tr4];
        float4 hc = *(const float4*)&sH[n][tc4];
        float ha[4] = {he.x, he.y, he.z, he.w};
        float ca[4] = {hc.x, hc.y, hc.z, hc.w};
        #pragma unroll
        for (int a = 0; a < 4; a++)
            #pragma unroll
            for (int b = 0; b < 4; b++) m[a][b] += ha[a] * ca[b];
    }
    #pragma unroll
    for (int a = 0; a < 4; a++)
        *(float4*)&Gp[(tr4 + a) * DD + tc4] = make_float4(m[a][0], m[a][1], m[a][2], m[a][3]);
    if (t < DD) {
        float ss = 0.f;
        #pragma unroll 8
        for (int n = 0; n < RPB; n++) ss += sH[n][t];
        sp[t] = ss;
    }
}

// setup: weff/beff column-stripe (4 cols) for (batch bb, stripe S).
// One 17 KB LDS buffer W staged sequentially with G -> Wk -> Wq.
template <typename T>
__device__ void setup_body(const float* Gg, const float* sg,
    const void* wq, const void* bq, const void* wb, const void* bbv,
    const void* wk, const void* bk, const void* wv, const void* bv,
    float* weff, float* beff, int layer, int t, int bb, int S, float* scr)
{
    float (*W)[SHP]  = (float(*)[SHP])scr;            // 0    .. 4352
    float (*tS)[4]   = (float(*)[4])(scr + 4352);     // 4352 .. 4608
    float (*mS)[4]   = (float(*)[4])(scr + 4608);     // 4608 .. 4864
    float (*wvS)[4]  = (float(*)[4])(scr + 4864);     // 4864 .. 5120
    float* sS  = scr + 5120;
    float* bkS = scr + 5184;
    float* bqS = scr + 5248;
    float* suS = scr + 5312;
    float* bvS = scr + 5316;

    const int wOff = layer * DD * DD, bOff = layer * DD;
    for (int i = t; i < DD * DD; i += NT) W[i >> 6][i & 63] = Gg[bb * DD * DD + i];
    for (int i = t; i < DD * 4; i += NT)
        wvS[i >> 2][i & 3] = Acc<T>::ld(wv, wOff + (i >> 2) * DD + S + (i & 3));
    if (t < DD) {
        sS[t]  = sg[bb * DD + t];
        bkS[t] = Acc<T>::ld(bk, bOff + t);
        bqS[t] = Acc<T>::ld(bq, bOff + t);
    }
    if (t < 4) bvS[t] = Acc<T>::ld(bv, bOff + S + t);
    __syncthreads();

    const int r = t >> 2, j = t & 3;
    // P1: T'[:,S] = G.Wv[:,S] + s bv^T  (W = G, symmetric -> row read)
    {
        float a0 = 0.f, a1 = 0.f, a2 = 0.f, a3 = 0.f;
        for (int e = 0; e < DD; e += 4) {
            a0 += W[r][e]     * wvS[e][j];
            a1 += W[r][e + 1] * wvS[e + 1][j];
            a2 += W[r][e + 2] * wvS[e + 2][j];
            a3 += W[r][e + 3] * wvS[e + 3][j];
        }
        tS[r][j] = (a0 + a1) + (a2 + a3) + sS[r] * bvS[j];
        if (t < 4) {
            float u0 = 0.f;
            for (int d = 0; d < DD; d++) u0 += sS[d] * wvS[d][t];
            suS[t] = u0 + (float)NN * bvS[t];
        }
    }
    __syncthreads();                                   // G reads done
    for (int i = t; i < DD * DD; i += NT) W[i >> 6][i & 63] = Acc<T>::ld(wk, wOff + i);
    __syncthreads();
    // P2: M[:,S] = Wk^T.T' + bk su^T   (W = Wk)
    {
        float a0 = 0.f, a1 = 0.f, a2 = 0.f, a3 = 0.f;
        for (int d = 0; d < DD; d += 4) {
            a0 += W[d][r]     * tS[d][j];
            a1 += W[d + 1][r] * tS[d + 1][j];
            a2 += W[d + 2][r] * tS[d + 2][j];
            a3 += W[d + 3][r] * tS[d + 3][j];
        }
        mS[r][j] = (a0 + a1) + (a2 + a3) + bkS[r] * suS[j];
    }
    __syncthreads();                                   // Wk reads done
    for (int i = t; i < DD * DD; i += NT) W[i >> 6][i & 63] = Acc<T>::ld(wq, wOff + i);
    __syncthreads();
    // P3: weff[:,S] = Wb[:,S] + C0*Wq.M[:,S]; beff[S] = bb[S] + C0*bq.M[:,S]
    {
        float a0 = 0.f, a1 = 0.f, a2 = 0.f, a3 = 0.f;
        for (int e = 0; e < DD; e += 4) {
            a0 += W[r][e]     * mS[e][j];
            a1 += W[r][e + 1] * mS[e + 1][j];
            a2 += W[r][e + 2] * mS[e + 2][j];
            a3 += W[r][e + 3] * mS[e + 3][j];
        }
        weff[bb * DD * DD + r * DD + S + j] =
            Acc<T>::ld(wb, wOff + r * DD + S + j) + C0F * ((a0 + a1) + (a2 + a3));
        if (t < 4) {
            float u = 0.f;
            for (int e = 0; e < DD; e++) u += bqS[e] * mS[e][t];
            beff[bb * DD + S + t] = Acc<T>::ld(bbv, bOff + S + t) + C0F * u;
        }
    }
}

template <typename T>
__device__ void run_net(
    const void* x, const void* lw, const void* lb,
    const void* blkw, const void* blkb,
    const void* qw, const void* qb, const void* kw, const void* kb,
    const void* vw, const void* vb, const void* pw, const void* pb,
    void* out, float* Gpart, float* spart, float* Gg, float* sg,
    float* weff, float* beff, unsigned* bar,
    float (*sH)[SHP], float* scr, int blk, int t)
{
    const int row0 = blk * RPB;
    const int bb = row0 >> 12;
    const int r = t >> 4, c4 = (t & 15) << 2;

    // ---- lift: h rows into resident LDS; write G0/s0 partials ----
    #pragma unroll
    for (int a = 0; a < 2; a++) {
        const int row = r + 16 * a, gr = row0 + row;
        float x0 = Acc<T>::ld(x, gr * 3 + 0);
        float x1 = Acc<T>::ld(x, gr * 3 + 1);
        float x2 = Acc<T>::ld(x, gr * 3 + 2);
        float o[4];
        #pragma unroll
        for (int b = 0; b < 4; b++) {
            int c = c4 + b;
            o[b] = Acc<T>::ld(lb, c) + x0 * Acc<T>::ld(lw, c)
                 + x1 * Acc<T>::ld(lw, DD + c) + x2 * Acc<T>::ld(lw, 2 * DD + c);
        }
        *(float4*)&sH[row][c4] = make_float4(o[0], o[1], o[2], o[3]);
    }
    __syncthreads();
    accG_part(sH, t, Gpart + (size_t)blk * DD * DD, spart + (size_t)blk * DD);
    grid_barrier(bar, t);

    for (int layer = 0; layer < NLAYER; layer++) {
        // ---- combine: 128 blocks sum one G row each; 2 blocks sum s ----
        if (blk < 2 * DD) {
            float (*red)[DD] = (float(*)[DD])scr;
            const int batch = blk >> 6, grow = blk & 63;
            const int c = t & 63, pc = t >> 6;
            const float* src = Gpart + ((size_t)(batch * PPB) << 12) + grow * DD + c;
            float acc = 0.f;
            #pragma unroll 8
            for (int k = 0; k < 32; k++) acc += src[(size_t)(pc * 32 + k) << 12];
            red[pc][c] = acc;
            __syncthreads();
            if (t < DD)
                Gg[batch * DD * DD + grow * DD + t] =
                    (red[0][t] + red[1][t]) + (red[2][t] + red[3][t]);
        } else if (blk < 2 * DD + NB) {
            float (*red)[DD] = (float(*)[DD])scr;
            const int batch = blk - 2 * DD;
            const int c = t & 63, pc = t >> 6;
            float acc = 0.f;
            #pragma unroll 8
            for (int k = 0; k < 32; k++)
                acc += spart[(size_t)(batch * PPB + pc * 32 + k) * DD + c];
            red[pc][c] = acc;
            __syncthreads();
            if (t < DD)
                sg[batch * DD + t] = (red[0][t] + red[1][t]) + (red[2][t] + red[3][t]);
        }
        grid_barrier(bar, t);

        // ---- setup: 32 blocks compute weff/beff stripes ----
        if (blk < NB * 16)
            setup_body<T>(Gg, sg, qw, qb, blkw, blkb, kw, kb, vw, vb,
                          weff, beff, layer, t, blk >> 4, (blk & 15) << 2, scr);
        grid_barrier(bar, t);

        // ---- apply: all blocks, h' = gelu(h@weff+beff) on resident sH ----
        {
            float (*wE)[DD] = (float(*)[DD])scr;       // 16 KB, reuse scratch
            float* beS = scr + DD * DD;
            const float4* wsrc = (const float4*)(weff + (size_t)bb * DD * DD);
            float4* wdst = (float4*)&wE[0][0];
            for (int i = t; i < DD * DD / 4; i += NT) wdst[i] = wsrc[i];
            if (t < DD) beS[t] = beff[bb * DD + t];
            __syncthreads();

            float o[2][4];
            #pragma unroll
            for (int a = 0; a < 2; a++) {
                const int row = r + 16 * a;
                float acc[4];
                #pragma unroll
                for (int b = 0; b < 4; b++) acc[b] = beS[c4 + b];
                for (int d = 0; d < DD; d++) {
                    float hv = sH[row][d];
                    float4 w4 = *(const float4*)&wE[d][c4];
                    acc[0] += hv * w4.x; acc[1] += hv * w4.y;
                    acc[2] += hv * w4.z; acc[3] += hv * w4.w;
                }
                #pragma unroll
                for (int b = 0; b < 4; b++) o[a][b] = gelu_exact(acc[b]);
            }

            if (layer == NLAYER - 1) {
                float pbv = Acc<T>::ld(pb, 0);
                #pragma unroll
                for (int a = 0; a < 2; a++) {
                    float p = 0.f;
                    #pragma unroll
                    for (int b = 0; b < 4; b++) p += o[a][b] * Acc<T>::ld(pw, c4 + b);
                    p += __shfl_xor(p, 1);
                    p += __shfl_xor(p, 2);
                    p += __shfl_xor(p, 4);
                    p += __shfl_xor(p, 8);
                    if ((t & 15) == 0) Acc<T>::st(out, row0 + r + 16 * a, p + pbv);
                }
            } else {
                __syncthreads();   // own-row sH reads done before overwrite
                #pragma unroll
                for (int a = 0; a < 2; a++)
                    *(float4*)&sH[r + 16 * a][c4] =
                        make_float4(o[a][0], o[a][1], o[a][2], o[a][3]);
                __syncthreads();
                accG_part(sH, t, Gpart + (size_t)blk * DD * DD, spart + (size_t)blk * DD);
            }
        }
        if (layer < NLAYER - 1) grid_barrier(bar, t);
    }
}

__global__ __launch_bounds__(NT) void gno_kernel(
    const void* x, const void* lw, const void* lb,
    const void* blkw, const void* blkb,
    const void* qw, const void* qb, const void* kw, const void* kb,
    const void* vw, const void* vb, const void* pw, const void* pb,
    void* out, float* Gpart, float* spart, float* Gg, float* sg,
    float* weff, float* beff, unsigned* bar)
{
    __shared__ float sH[RPB][SHP];   //  8704 B: resident h rows
    __shared__ float scr[SCRN];      // 21280 B: phase-union scratch
    __shared__ int stot;

    const int blk = blockIdx.x, t = threadIdx.x;

    // dtype detect: every block scans the same 8192 words -> same answer
    if (t == 0) stot = 0;
    __syncthreads();
    int cnt = 0;
    const unsigned int* xw = (const unsigned int*)x;
    for (int i = t; i < 8192; i += NT) {
        unsigned u = xw[i] & 0xFFFFu;
        int e = (u >> 7) & 0xFF;
        cnt += (u == 0u || (e >= 100 && e <= 142)) ? 1 : 0;
    }
    atomicAdd(&stot, cnt);
    __syncthreads();
    const bool isbf = (stot > 4915);

    if (isbf)
        run_net<bf16>(x, lw, lb, blkw, blkb, qw, qb, kw, kb, vw, vb, pw, pb,
                      out, Gpart, spart, Gg, sg, weff, beff, bar, sH, scr, blk, t);
    else
        run_net<float>(x, lw, lb, blkw, blkb, qw, qb, kw, kb, vw, vb, pw, pb,
                       out, Gpart, spart, Gg, sg, weff, beff, bar, sH, scr, blk, t);
}

extern "C" void kernel_launch(void* const* d_in, const int* in_sizes, int n_in,
                              void* d_out, int out_size, void* d_ws, size_t ws_size,
                              hipStream_t stream)
{
    const void* x    = d_in[0];
    const void* lw   = d_in[1];
    const void* lb   = d_in[2];
    const void* blkw = d_in[3];
    const void* blkb = d_in[4];
    const void* qw   = d_in[5];
    const void* qb   = d_in[6];
    const void* kw   = d_in[7];
    const void* kb   = d_in[8];
    const void* vw   = d_in[9];
    const void* vb   = d_in[10];
    const void* pw   = d_in[11];
    const void* pb   = d_in[12];

    unsigned* bar = (unsigned*)d_ws;                      // [16] barrier counter
    float* Gpart  = (float*)d_ws + 16;                    // [256][64][64] 4 MB
    float* spart  = Gpart + (size_t)NBLK * DD * DD;       // [256][64]
    float* Gg     = spart + (size_t)NBLK * DD;            // [2][64][64]
    float* sg     = Gg + (size_t)NB * DD * DD;            // [2][64]
    float* weff   = sg + (size_t)NB * DD;                 // [2][64][64]
    float* beff   = weff + (size_t)NB * DD * DD;          // [2][64]

    hipMemsetAsync(bar, 0, 16 * sizeof(unsigned), stream);
    gno_kernel<<<NBLK, NT, 0, stream>>>(x, lw, lb, blkw, blkb, qw, qb, kw, kb,
                                        vw, vb, pw, pb, d_out,
                                        Gpart, spart, Gg, sg, weff, beff, bar);
}

// Round 8
// 203.296 us; speedup vs baseline: 2.7314x; 2.7314x over previous
//
#include <hip/hip_runtime.h>
#include <hip/hip_bf16.h>
#include <math.h>

// GNO collapsed: h = lift(x); per layer h = gelu(h@weff + beff) where
//   weff = Wb + c0*Wq@M, beff = bb + c0*bq@M,
//   M = Wk^T G Wv + (Wk^T s) bv^T + bk (s^T Wv) + N bk bv^T, G = h^T h, s = h^T 1.
// Round 8: same persistent structure as round 7 (passed, traffic 31 MB) but the
// barrier is rebuilt: per-block arrive flags + single release word (no contended
// RMW -> round 7 spent 41 us/barrier on 256 serialized line-RMWs + L2 wb/inv),
// and ALL cross-block data uses relaxed agent-scope (sc1, device-coherent)
// loads/stores so no cache-flush fences are needed anywhere.

#define NLAYER 4
#define NB 2
#define NN 4096
#define DD 64
#define RPB 32              // rows per block (8192 rows / 256 blocks)
#define NT 256
#define NBLK 256
#define PPB 128             // G-partial slots per batch
#define C0F (1.0f/32768.0f) // (1/sqrt(64))/4096
#define SHP 68              // padded LDS stride
#define SCRN 5320           // scratch floats

typedef __hip_bfloat16 bf16;

__device__ __forceinline__ float b2f(const bf16 v) { return __bfloat162float(v); }

template <typename T> struct Acc;
template <> struct Acc<float> {
    static __device__ __forceinline__ float ld(const void* p, int i) { return ((const float*)p)[i]; }
    static __device__ __forceinline__ void st(void* p, int i, float v) { ((float*)p)[i] = v; }
};
template <> struct Acc<bf16> {
    static __device__ __forceinline__ float ld(const void* p, int i) { return b2f(((const bf16*)p)[i]); }
    static __device__ __forceinline__ void st(void* p, int i, float v) { ((bf16*)p)[i] = __float2bfloat16(v); }
};

__device__ __forceinline__ float gelu_exact(float x) {
    return 0.5f * x * (1.0f + erff(x * 0.70710678118654752f));
}

// Device-coherent (agent-scope, relaxed) scalar access: per-access sc1
// coherence instead of whole-L2 writeback/invalidate fences.
__device__ __forceinline__ float ldc(const float* p) {
    unsigned u = __hip_atomic_load((unsigned*)p, __ATOMIC_RELAXED, __HIP_MEMORY_SCOPE_AGENT);
    return __uint_as_float(u);
}
__device__ __forceinline__ void stc(float* p, float v) {
    __hip_atomic_store((unsigned*)p, __float_as_uint(v), __ATOMIC_RELAXED, __HIP_MEMORY_SCOPE_AGENT);
}
__device__ __forceinline__ unsigned ldw(unsigned* p) {
    return __hip_atomic_load(p, __ATOMIC_RELAXED, __HIP_MEMORY_SCOPE_AGENT);
}
__device__ __forceinline__ void stw(unsigned* p, unsigned v) {
    __hip_atomic_store(p, v, __ATOMIC_RELAXED, __HIP_MEMORY_SCOPE_AGENT);
}

// Contention-free grid barrier. bar[1..255]: per-block arrive epochs;
// bar[320]: release epoch. Monotone epochs (>= compare) make reuse race-free.
// Ordering: __syncthreads drains vmcnt(0) per wave, so all of a block's sc1
// data stores are at the coherence point before t0's arrive store issues.
// Bounded spins: a co-residency failure shows as wrong output, not a hang.
__device__ void grid_barrier(unsigned* bar, int blk, int t, unsigned epoch) {
    __syncthreads();
    if (blk == 0) {
        if (t > 0) {   // thread t waits for block t's arrival
            int guard = 0;
            while (ldw(&bar[t]) < epoch && ++guard < (1 << 17))
                __builtin_amdgcn_s_sleep(8);
        }
        __syncthreads();
        if (t == 0) stw(&bar[320], epoch);
    } else {
        if (t == 0) {
            stw(&bar[blk], epoch);
            int guard = 0;
            while (ldw(&bar[320]) < epoch && ++guard < (1 << 17))
                __builtin_amdgcn_s_sleep(8);
        }
        __syncthreads();
    }
}

// G-partial (4x4 tile/thread over RPB LDS rows) + s-partial, coherent stores.
__device__ __forceinline__ void accG_part(const float (*sH)[SHP], int t,
                                          float* __restrict__ Gp, float* __restrict__ sp)
{
    const int tr4 = (t >> 4) << 2, tc4 = (t & 15) << 2;
    float m[4][4];
    #pragma unroll
    for (int a = 0; a < 4; a++)
        #pragma unroll
        for (int b = 0; b < 4; b++) m[a][b] = 0.f;
    #pragma unroll 8
    for (int n = 0; n < RPB; n++) {
        float4 he = *(const float4*)&sH[n][tr4];
        float4 hc = *(const float4*)&sH[n][tc4];
        float ha[4] = {he.x, he.y, he.z, he.w};
        float ca[4] = {hc.x, hc.y, hc.z, hc.w};
        #pragma unroll
        for (int a = 0; a < 4; a++)
            #pragma unroll
            for (int b = 0; b < 4; b++) m[a][b] += ha[a] * ca[b];
    }
    #pragma unroll
    for (int a = 0; a < 4; a++)
        #pragma unroll
        for (int b = 0; b < 4; b++)
            stc(&Gp[(tr4 + a) * DD + tc4 + b], m[a][b]);
    if (t < DD) {
        float ss = 0.f;
        #pragma unroll 8
        for (int n = 0; n < RPB; n++) ss += sH[n][t];
        stc(&sp[t], ss);
    }
}

// setup: weff/beff column-stripe (4 cols) for (batch bb, stripe S).
// One 17 KB LDS buffer W staged sequentially with G -> Wk -> Wq.
template <typename T>
__device__ void setup_body(const float* Gg, const float* sg,
    const void* wq, const void* bq, const void* wb, const void* bbv,
    const void* wk, const void* bk, const void* wv, const void* bv,
    float* weff, float* beff, int layer, int t, int bb, int S, float* scr)
{
    float (*W)[SHP]  = (float(*)[SHP])scr;
    float (*tS)[4]   = (float(*)[4])(scr + 4352);
    float (*mS)[4]   = (float(*)[4])(scr + 4608);
    float (*wvS)[4]  = (float(*)[4])(scr + 4864);
    float* sS  = scr + 5120;
    float* bkS = scr + 5184;
    float* bqS = scr + 5248;
    float* suS = scr + 5312;
    float* bvS = scr + 5316;

    const int wOff = layer * DD * DD, bOff = layer * DD;
    for (int i = t; i < DD * DD; i += NT) W[i >> 6][i & 63] = ldc(&Gg[bb * DD * DD + i]);
    for (int i = t; i < DD * 4; i += NT)
        wvS[i >> 2][i & 3] = Acc<T>::ld(wv, wOff + (i >> 2) * DD + S + (i & 3));
    if (t < DD) {
        sS[t]  = ldc(&sg[bb * DD + t]);
        bkS[t] = Acc<T>::ld(bk, bOff + t);
        bqS[t] = Acc<T>::ld(bq, bOff + t);
    }
    if (t < 4) bvS[t] = Acc<T>::ld(bv, bOff + S + t);
    __syncthreads();

    const int r = t >> 2, j = t & 3;
    // P1: T'[:,S] = G.Wv[:,S] + s bv^T  (W = G, symmetric -> row read)
    {
        float a0 = 0.f, a1 = 0.f, a2 = 0.f, a3 = 0.f;
        for (int e = 0; e < DD; e += 4) {
            a0 += W[r][e]     * wvS[e][j];
            a1 += W[r][e + 1] * wvS[e + 1][j];
            a2 += W[r][e + 2] * wvS[e + 2][j];
            a3 += W[r][e + 3] * wvS[e + 3][j];
        }
        tS[r][j] = (a0 + a1) + (a2 + a3) + sS[r] * bvS[j];
        if (t < 4) {
            float u0 = 0.f;
            for (int d = 0; d < DD; d++) u0 += sS[d] * wvS[d][t];
            suS[t] = u0 + (float)NN * bvS[t];
        }
    }
    __syncthreads();
    for (int i = t; i < DD * DD; i += NT) W[i >> 6][i & 63] = Acc<T>::ld(wk, wOff + i);
    __syncthreads();
    // P2: M[:,S] = Wk^T.T' + bk su^T   (W = Wk)
    {
        float a0 = 0.f, a1 = 0.f, a2 = 0.f, a3 = 0.f;
        for (int d = 0; d < DD; d += 4) {
            a0 += W[d][r]     * tS[d][j];
            a1 += W[d + 1][r] * tS[d + 1][j];
            a2 += W[d + 2][r] * tS[d + 2][j];
            a3 += W[d + 3][r] * tS[d + 3][j];
        }
        mS[r][j] = (a0 + a1) + (a2 + a3) + bkS[r] * suS[j];
    }
    __syncthreads();
    for (int i = t; i < DD * DD; i += NT) W[i >> 6][i & 63] = Acc<T>::ld(wq, wOff + i);
    __syncthreads();
    // P3: weff[:,S] = Wb[:,S] + C0*Wq.M[:,S]; beff[S] = bb[S] + C0*bq.M[:,S]
    {
        float a0 = 0.f, a1 = 0.f, a2 = 0.f, a3 = 0.f;
        for (int e = 0; e < DD; e += 4) {
            a0 += W[r][e]     * mS[e][j];
            a1 += W[r][e + 1] * mS[e + 1][j];
            a2 += W[r][e + 2] * mS[e + 2][j];
            a3 += W[r][e + 3] * mS[e + 3][j];
        }
        stc(&weff[bb * DD * DD + r * DD + S + j],
            Acc<T>::ld(wb, wOff + r * DD + S + j) + C0F * ((a0 + a1) + (a2 + a3)));
        if (t < 4) {
            float u = 0.f;
            for (int e = 0; e < DD; e++) u += bqS[e] * mS[e][t];
            stc(&beff[bb * DD + S + t], Acc<T>::ld(bbv, bOff + S + t) + C0F * u);
        }
    }
}

template <typename T>
__device__ void run_net(
    const void* x, const void* lw, const void* lb,
    const void* blkw, const void* blkb,
    const void* qw, const void* qb, const void* kw, const void* kb,
    const void* vw, const void* vb, const void* pw, const void* pb,
    void* out, float* Gpart, float* spart, float* Gg, float* sg,
    float* weff, float* beff, unsigned* bar,
    float (*sH)[SHP], float* scr, int blk, int t)
{
    const int row0 = blk * RPB;
    const int bb = row0 >> 12;
    const int r = t >> 4, c4 = (t & 15) << 2;
    unsigned ep = 0;

    // ---- lift: h rows into resident LDS; write G0/s0 partials ----
    #pragma unroll
    for (int a = 0; a < 2; a++) {
        const int row = r + 16 * a, gr = row0 + row;
        float x0 = Acc<T>::ld(x, gr * 3 + 0);
        float x1 = Acc<T>::ld(x, gr * 3 + 1);
        float x2 = Acc<T>::ld(x, gr * 3 + 2);
        float o[4];
        #pragma unroll
        for (int b = 0; b < 4; b++) {
            int c = c4 + b;
            o[b] = Acc<T>::ld(lb, c) + x0 * Acc<T>::ld(lw, c)
                 + x1 * Acc<T>::ld(lw, DD + c) + x2 * Acc<T>::ld(lw, 2 * DD + c);
        }
        *(float4*)&sH[row][c4] = make_float4(o[0], o[1], o[2], o[3]);
    }
    __syncthreads();
    accG_part(sH, t, Gpart + (size_t)blk * DD * DD, spart + (size_t)blk * DD);
    grid_barrier(bar, blk, t, ++ep);

    for (int layer = 0; layer < NLAYER; layer++) {
        // ---- combine: 128 blocks sum one G row each; 2 blocks sum s ----
        if (blk < 2 * DD) {
            float (*red)[DD] = (float(*)[DD])scr;
            const int batch = blk >> 6, grow = blk & 63;
            const int c = t & 63, pc = t >> 6;
            const float* src = Gpart + ((size_t)(batch * PPB) << 12) + grow * DD + c;
            float acc = 0.f;
            #pragma unroll 8
            for (int k = 0; k < 32; k++) acc += ldc(&src[(size_t)(pc * 32 + k) << 12]);
            red[pc][c] = acc;
            __syncthreads();
            if (t < DD)
                stc(&Gg[batch * DD * DD + grow * DD + t],
                    (red[0][t] + red[1][t]) + (red[2][t] + red[3][t]));
        } else if (blk < 2 * DD + NB) {
            float (*red)[DD] = (float(*)[DD])scr;
            const int batch = blk - 2 * DD;
            const int c = t & 63, pc = t >> 6;
            float acc = 0.f;
            #pragma unroll 8
            for (int k = 0; k < 32; k++)
                acc += ldc(&spart[(size_t)(batch * PPB + pc * 32 + k) * DD + c]);
            red[pc][c] = acc;
            __syncthreads();
            if (t < DD)
                stc(&sg[batch * DD + t],
                    (red[0][t] + red[1][t]) + (red[2][t] + red[3][t]));
        }
        grid_barrier(bar, blk, t, ++ep);

        // ---- setup: 32 blocks compute weff/beff stripes ----
        if (blk < NB * 16)
            setup_body<T>(Gg, sg, qw, qb, blkw, blkb, kw, kb, vw, vb,
                          weff, beff, layer, t, blk >> 4, (blk & 15) << 2, scr);
        grid_barrier(bar, blk, t, ++ep);

        // ---- apply: all blocks, h' = gelu(h@weff+beff) on resident sH ----
        {
            float (*wE)[DD] = (float(*)[DD])scr;
            float* beS = scr + DD * DD;
            for (int i = t; i < DD * DD; i += NT)
                wE[i >> 6][i & 63] = ldc(&weff[(size_t)bb * DD * DD + i]);
            if (t < DD) beS[t] = ldc(&beff[bb * DD + t]);
            __syncthreads();

            float o[2][4];
            #pragma unroll
            for (int a = 0; a < 2; a++) {
                const int row = r + 16 * a;
                float acc[4];
                #pragma unroll
                for (int b = 0; b < 4; b++) acc[b] = beS[c4 + b];
                for (int d = 0; d < DD; d++) {
                    float hv = sH[row][d];
                    float4 w4 = *(const float4*)&wE[d][c4];
                    acc[0] += hv * w4.x; acc[1] += hv * w4.y;
                    acc[2] += hv * w4.z; acc[3] += hv * w4.w;
                }
                #pragma unroll
                for (int b = 0; b < 4; b++) o[a][b] = gelu_exact(acc[b]);
            }

            if (layer == NLAYER - 1) {
                float pbv = Acc<T>::ld(pb, 0);
                #pragma unroll
                for (int a = 0; a < 2; a++) {
                    float p = 0.f;
                    #pragma unroll
                    for (int b = 0; b < 4; b++) p += o[a][b] * Acc<T>::ld(pw, c4 + b);
                    p += __shfl_xor(p, 1);
                    p += __shfl_xor(p, 2);
                    p += __shfl_xor(p, 4);
                    p += __shfl_xor(p, 8);
                    if ((t & 15) == 0) Acc<T>::st(out, row0 + r + 16 * a, p + pbv);
                }
            } else {
                __syncthreads();   // own-row sH reads done before overwrite
                #pragma unroll
                for (int a = 0; a < 2; a++)
                    *(float4*)&sH[r + 16 * a][c4] =
                        make_float4(o[a][0], o[a][1], o[a][2], o[a][3]);
                __syncthreads();
                accG_part(sH, t, Gpart + (size_t)blk * DD * DD, spart + (size_t)blk * DD);
            }
        }
        if (layer < NLAYER - 1) grid_barrier(bar, blk, t, ++ep);
    }
}

__global__ __launch_bounds__(NT) void gno_kernel(
    const void* x, const void* lw, const void* lb,
    const void* blkw, const void* blkb,
    const void* qw, const void* qb, const void* kw, const void* kb,
    const void* vw, const void* vb, const void* pw, const void* pb,
    void* out, float* Gpart, float* spart, float* Gg, float* sg,
    float* weff, float* beff, unsigned* bar)
{
    __shared__ float sH[RPB][SHP];   //  8704 B: resident h rows
    __shared__ float scr[SCRN];      // 21280 B: phase-union scratch
    __shared__ int stot;

    const int blk = blockIdx.x, t = threadIdx.x;

    // dtype detect: every block scans the same 8192 words -> same answer
    if (t == 0) stot = 0;
    __syncthreads();
    int cnt = 0;
    const unsigned int* xw = (const unsigned int*)x;
    for (int i = t; i < 8192; i += NT) {
        unsigned u = xw[i] & 0xFFFFu;
        int e = (u >> 7) & 0xFF;
        cnt += (u == 0u || (e >= 100 && e <= 142)) ? 1 : 0;
    }
    atomicAdd(&stot, cnt);
    __syncthreads();
    const bool isbf = (stot > 4915);

    if (isbf)
        run_net<bf16>(x, lw, lb, blkw, blkb, qw, qb, kw, kb, vw, vb, pw, pb,
                      out, Gpart, spart, Gg, sg, weff, beff, bar, sH, scr, blk, t);
    else
        run_net<float>(x, lw, lb, blkw, blkb, qw, qb, kw, kb, vw, vb, pw, pb,
                       out, Gpart, spart, Gg, sg, weff, beff, bar, sH, scr, blk, t);
}

extern "C" void kernel_launch(void* const* d_in, const int* in_sizes, int n_in,
                              void* d_out, int out_size, void* d_ws, size_t ws_size,
                              hipStream_t stream)
{
    const void* x    = d_in[0];
    const void* lw   = d_in[1];
    const void* lb   = d_in[2];
    const void* blkw = d_in[3];
    const void* blkb = d_in[4];
    const void* qw   = d_in[5];
    const void* qb   = d_in[6];
    const void* kw   = d_in[7];
    const void* kb   = d_in[8];
    const void* vw   = d_in[9];
    const void* vb   = d_in[10];
    const void* pw   = d_in[11];
    const void* pb   = d_in[12];

    unsigned* bar = (unsigned*)d_ws;                      // [384] barrier words
    float* Gpart  = (float*)d_ws + 384;                   // [256][64][64] 4 MB
    float* spart  = Gpart + (size_t)NBLK * DD * DD;       // [256][64]
    float* Gg     = spart + (size_t)NBLK * DD;            // [2][64][64]
    float* sg     = Gg + (size_t)NB * DD * DD;            // [2][64]
    float* weff   = sg + (size_t)NB * DD;                 // [2][64][64]
    float* beff   = weff + (size_t)NB * DD * DD;          // [2][64]

    hipMemsetAsync(bar, 0, 384 * sizeof(unsigned), stream);
    gno_kernel<<<NBLK, NT, 0, stream>>>(x, lw, lb, blkw, blkb, qw, qb, kw, kb,
                                        vw, vb, pw, pb, d_out,
                                        Gpart, spart, Gg, sg, weff, beff, bar);
}

// Round 9
// 201.428 us; speedup vs baseline: 2.7567x; 1.0093x over previous
//
#include <hip/hip_runtime.h>
#include <hip/hip_bf16.h>
#include <math.h>

// GNO collapsed: h = lift(x); per layer h = gelu(h@weff + beff) where
//   weff = Wb + c0*Wq@M, beff = bb + c0*bq@M,
//   M = Wk^T G Wv + (Wk^T s) bv^T + bk (s^T Wv) + N bk bv^T, G = h^T h, s = h^T 1.
// Round 9: dataflow pipeline. No full-grid barriers at all -- per-stage epoch
// flags (apply->combine->setup->apply), 8-byte sc1 coherent accesses everywhere
// (round 8's 4B write-through inflated WRITE 18->66 MB via partial-line RMW and
// its 12 full-grid barriers cost ~120 of 135 us).
// Roles: blocks 0..127 combine G-rows, 128..129 combine s, 130..161 setup
// weff stripes; ALL 256 blocks lift/apply (h resident in LDS throughout).

#define NLAYER 4
#define NB 2
#define NN 4096
#define DD 64
#define RPB 32              // rows per block (8192 rows / 256 blocks)
#define NT 256
#define NBLK 256
#define PPB 128             // G-partial slots per batch
#define C0F (1.0f/32768.0f) // (1/sqrt(64))/4096
#define SHP 68              // padded LDS stride
#define SCRN 5320           // scratch floats

typedef __hip_bfloat16 bf16;
typedef unsigned long long u64t;

__device__ __forceinline__ float b2f(const bf16 v) { return __bfloat162float(v); }

template <typename T> struct Acc;
template <> struct Acc<float> {
    static __device__ __forceinline__ float ld(const void* p, int i) { return ((const float*)p)[i]; }
    static __device__ __forceinline__ void st(void* p, int i, float v) { ((float*)p)[i] = v; }
};
template <> struct Acc<bf16> {
    static __device__ __forceinline__ float ld(const void* p, int i) { return b2f(((const bf16*)p)[i]); }
    static __device__ __forceinline__ void st(void* p, int i, float v) { ((bf16*)p)[i] = __float2bfloat16(v); }
};

__device__ __forceinline__ float gelu_exact(float x) {
    return 0.5f * x * (1.0f + erff(x * 0.70710678118654752f));
}

// Device-coherent (agent-scope, relaxed) accesses: per-access sc1 coherence,
// no cache-flush fences anywhere. 8-byte where layout permits.
__device__ __forceinline__ float ldc(const float* p) {
    unsigned u = __hip_atomic_load((const unsigned*)p, __ATOMIC_RELAXED, __HIP_MEMORY_SCOPE_AGENT);
    return __uint_as_float(u);
}
__device__ __forceinline__ void stc(float* p, float v) {
    __hip_atomic_store((unsigned*)p, __float_as_uint(v), __ATOMIC_RELAXED, __HIP_MEMORY_SCOPE_AGENT);
}
__device__ __forceinline__ float2 ldc2(const float* p) {
    u64t v = __hip_atomic_load((const u64t*)p, __ATOMIC_RELAXED, __HIP_MEMORY_SCOPE_AGENT);
    float2 r;
    r.x = __uint_as_float((unsigned)v);
    r.y = __uint_as_float((unsigned)(v >> 32));
    return r;
}
__device__ __forceinline__ void stc2(float* p, float a, float b) {
    u64t v = ((u64t)__float_as_uint(b) << 32) | (u64t)__float_as_uint(a);
    __hip_atomic_store((u64t*)p, v, __ATOMIC_RELAXED, __HIP_MEMORY_SCOPE_AGENT);
}
__device__ __forceinline__ unsigned ldw(unsigned* p) {
    return __hip_atomic_load(p, __ATOMIC_RELAXED, __HIP_MEMORY_SCOPE_AGENT);
}
__device__ __forceinline__ void stw(unsigned* p, unsigned v) {
    __hip_atomic_store(p, v, __ATOMIC_RELAXED, __HIP_MEMORY_SCOPE_AGENT);
}
// Poll one epoch word until >= ep. Ordering: the producer's __syncthreads
// (vmcnt(0) drain in every wave) precedes its flag store, so flag-visibility
// implies data-visibility at the coherence point; consumer reads via sc1.
__device__ __forceinline__ void pollw(unsigned* p, unsigned ep) {
    int guard = 0;
    while (ldw(p) < ep && ++guard < (1 << 17)) __builtin_amdgcn_s_sleep(8);
}

// G-partial (4x4 tile/thread over RPB LDS rows) + s-partial, coherent 8B stores.
__device__ __forceinline__ void accG_part(const float (*sH)[SHP], int t,
                                          float* __restrict__ Gp, float* __restrict__ sp)
{
    const int tr4 = (t >> 4) << 2, tc4 = (t & 15) << 2;
    float m[4][4];
    #pragma unroll
    for (int a = 0; a < 4; a++)
        #pragma unroll
        for (int b = 0; b < 4; b++) m[a][b] = 0.f;
    #pragma unroll 8
    for (int n = 0; n < RPB; n++) {
        float4 he = *(const float4*)&sH[n][tr4];
        float4 hc = *(const float4*)&sH[n][tc4];
        float ha[4] = {he.x, he.y, he.z, he.w};
        float ca[4] = {hc.x, hc.y, hc.z, hc.w};
        #pragma unroll
        for (int a = 0; a < 4; a++)
            #pragma unroll
            for (int b = 0; b < 4; b++) m[a][b] += ha[a] * ca[b];
    }
    #pragma unroll
    for (int a = 0; a < 4; a++) {
        stc2(&Gp[(tr4 + a) * DD + tc4], m[a][0], m[a][1]);
        stc2(&Gp[(tr4 + a) * DD + tc4 + 2], m[a][2], m[a][3]);
    }
    if (t < DD) {
        float ss = 0.f;
        #pragma unroll 8
        for (int n = 0; n < RPB; n++) ss += sH[n][t];
        stc(&sp[t], ss);
    }
}

// setup: weff/beff column-stripe (4 cols) for (batch bb, stripe S).
// One 17 KB LDS buffer W staged sequentially with G -> Wk -> Wq.
template <typename T>
__device__ void setup_body(const float* Gg, const float* sg,
    const void* wq, const void* bq, const void* wb, const void* bbv,
    const void* wk, const void* bk, const void* wv, const void* bv,
    float* weff, float* beff, int layer, int t, int bb, int S, float* scr)
{
    float (*W)[SHP]  = (float(*)[SHP])scr;
    float (*tS)[4]   = (float(*)[4])(scr + 4352);
    float (*mS)[4]   = (float(*)[4])(scr + 4608);
    float (*wvS)[4]  = (float(*)[4])(scr + 4864);
    float* sS  = scr + 5120;
    float* bkS = scr + 5184;
    float* bqS = scr + 5248;
    float* suS = scr + 5312;
    float* bvS = scr + 5316;

    const int wOff = layer * DD * DD, bOff = layer * DD;
    for (int i = t; i < DD * DD / 2; i += NT) {
        float2 v = ldc2(&Gg[bb * DD * DD + 2 * i]);
        const int idx = 2 * i;
        W[idx >> 6][idx & 63] = v.x;
        W[idx >> 6][(idx & 63) + 1] = v.y;
    }
    for (int i = t; i < DD * 4; i += NT)
        wvS[i >> 2][i & 3] = Acc<T>::ld(wv, wOff + (i >> 2) * DD + S + (i & 3));
    if (t < DD) {
        sS[t]  = ldc(&sg[bb * DD + t]);
        bkS[t] = Acc<T>::ld(bk, bOff + t);
        bqS[t] = Acc<T>::ld(bq, bOff + t);
    }
    if (t < 4) bvS[t] = Acc<T>::ld(bv, bOff + S + t);
    __syncthreads();

    const int r = t >> 2, j = t & 3;
    // P1: T'[:,S] = G.Wv[:,S] + s bv^T  (W = G, symmetric -> row read)
    {
        float a0 = 0.f, a1 = 0.f, a2 = 0.f, a3 = 0.f;
        for (int e = 0; e < DD; e += 4) {
            a0 += W[r][e]     * wvS[e][j];
            a1 += W[r][e + 1] * wvS[e + 1][j];
            a2 += W[r][e + 2] * wvS[e + 2][j];
            a3 += W[r][e + 3] * wvS[e + 3][j];
        }
        tS[r][j] = (a0 + a1) + (a2 + a3) + sS[r] * bvS[j];
        if (t < 4) {
            float u0 = 0.f;
            for (int d = 0; d < DD; d++) u0 += sS[d] * wvS[d][t];
            suS[t] = u0 + (float)NN * bvS[t];
        }
    }
    __syncthreads();
    for (int i = t; i < DD * DD; i += NT) W[i >> 6][i & 63] = Acc<T>::ld(wk, wOff + i);
    __syncthreads();
    // P2: M[:,S] = Wk^T.T' + bk su^T   (W = Wk)
    {
        float a0 = 0.f, a1 = 0.f, a2 = 0.f, a3 = 0.f;
        for (int d = 0; d < DD; d += 4) {
            a0 += W[d][r]     * tS[d][j];
            a1 += W[d + 1][r] * tS[d + 1][j];
            a2 += W[d + 2][r] * tS[d + 2][j];
            a3 += W[d + 3][r] * tS[d + 3][j];
        }
        mS[r][j] = (a0 + a1) + (a2 + a3) + bkS[r] * suS[j];
    }
    __syncthreads();
    for (int i = t; i < DD * DD; i += NT) W[i >> 6][i & 63] = Acc<T>::ld(wq, wOff + i);
    __syncthreads();
    // P3: weff[:,S] = Wb[:,S] + C0*Wq.M[:,S]; beff[S] = bb[S] + C0*bq.M[:,S]
    {
        float a0 = 0.f, a1 = 0.f, a2 = 0.f, a3 = 0.f;
        for (int e = 0; e < DD; e += 4) {
            a0 += W[r][e]     * mS[e][j];
            a1 += W[r][e + 1] * mS[e + 1][j];
            a2 += W[r][e + 2] * mS[e + 2][j];
            a3 += W[r][e + 3] * mS[e + 3][j];
        }
        stc(&weff[bb * DD * DD + r * DD + S + j],
            Acc<T>::ld(wb, wOff + r * DD + S + j) + C0F * ((a0 + a1) + (a2 + a3)));
        if (t < 4) {
            float u = 0.f;
            for (int e = 0; e < DD; e++) u += bqS[e] * mS[e][t];
            stc(&beff[bb * DD + S + t], Acc<T>::ld(bbv, bOff + S + t) + C0F * u);
        }
    }
}

template <typename T>
__device__ void run_net(
    const void* x, const void* lw, const void* lb,
    const void* blkw, const void* blkb,
    const void* qw, const void* qb, const void* kw, const void* kb,
    const void* vw, const void* vb, const void* pw, const void* pb,
    void* out, float* Gpart, float* spart, float* Gg, float* sg,
    float* weff, float* beff, unsigned* bar,
    float (*sH)[SHP], float* scr, int blk, int t)
{
    unsigned* aflag = bar;            // [256] apply/lift done epochs
    unsigned* cflag = bar + 256;      // [130] combine done epochs
    unsigned* sflag = bar + 392;      // [32]  setup done epochs

    const int row0 = blk * RPB;
    const int bb = row0 >> 12;
    const int r = t >> 4, c4 = (t & 15) << 2;

    // ---- lift: h rows into resident LDS; write G0/s0 partials ----
    #pragma unroll
    for (int a = 0; a < 2; a++) {
        const int row = r + 16 * a, gr = row0 + row;
        float x0 = Acc<T>::ld(x, gr * 3 + 0);
        float x1 = Acc<T>::ld(x, gr * 3 + 1);
        float x2 = Acc<T>::ld(x, gr * 3 + 2);
        float o[4];
        #pragma unroll
        for (int b = 0; b < 4; b++) {
            int c = c4 + b;
            o[b] = Acc<T>::ld(lb, c) + x0 * Acc<T>::ld(lw, c)
                 + x1 * Acc<T>::ld(lw, DD + c) + x2 * Acc<T>::ld(lw, 2 * DD + c);
        }
        *(float4*)&sH[row][c4] = make_float4(o[0], o[1], o[2], o[3]);
    }
    __syncthreads();
    accG_part(sH, t, Gpart + (size_t)blk * DD * DD, spart + (size_t)blk * DD);
    __syncthreads();                        // all Gpart stores drained (vmcnt 0)
    if (t == 0) stw(&aflag[blk], 1u);

    for (int layer = 0; layer < NLAYER; layer++) {
        const unsigned ep = (unsigned)(layer + 1);

        // ---- combine (blocks 0..129): wait all 256 partials, reduce ----
        if (blk < 2 * DD + NB) {
            pollw(&aflag[t], ep);           // thread t waits block t's partial
            __syncthreads();
            float (*red)[DD] = (float(*)[DD])scr;   // [8][64]
            const int cp = t & 31, kg = t >> 5;     // 32 col-pairs x 8 k-groups
            if (blk < 2 * DD) {
                const int batch = blk >> 6, grow = blk & 63;
                const float* base = Gpart + ((size_t)(batch * PPB) << 12) + grow * DD + 2 * cp;
                float ax = 0.f, ay = 0.f;
                #pragma unroll 4
                for (int k = 0; k < 16; k++) {
                    float2 v = ldc2(&base[(size_t)(kg * 16 + k) << 12]);
                    ax += v.x; ay += v.y;
                }
                red[kg][2 * cp] = ax; red[kg][2 * cp + 1] = ay;
                __syncthreads();
                if (t < 32) {
                    float s0 = 0.f, s1 = 0.f;
                    #pragma unroll
                    for (int g = 0; g < 8; g++) { s0 += red[g][2 * t]; s1 += red[g][2 * t + 1]; }
                    stc2(&Gg[batch * DD * DD + grow * DD + 2 * t], s0, s1);
                }
            } else {
                const int batch = blk - 2 * DD;
                float ax = 0.f, ay = 0.f;
                #pragma unroll 4
                for (int k = 0; k < 16; k++) {
                    float2 v = ldc2(&spart[(size_t)(batch * PPB + kg * 16 + k) * DD + 2 * cp]);
                    ax += v.x; ay += v.y;
                }
                red[kg][2 * cp] = ax; red[kg][2 * cp + 1] = ay;
                __syncthreads();
                if (t < 32) {
                    float s0 = 0.f, s1 = 0.f;
                    #pragma unroll
                    for (int g = 0; g < 8; g++) { s0 += red[g][2 * t]; s1 += red[g][2 * t + 1]; }
                    stc2(&sg[batch * DD + 2 * t], s0, s1);
                }
            }
            __syncthreads();                // Gg/sg stores drained
            if (t == 0) stw(&cflag[blk], ep);
        }

        // ---- setup (blocks 130..161): wait 130 combine flags, build weff ----
        if (blk >= 2 * DD + NB && blk < 2 * DD + NB + NB * 16) {
            const int sb = blk - (2 * DD + NB);
            if (t < 2 * DD + NB) pollw(&cflag[t], ep);
            __syncthreads();
            setup_body<T>(Gg, sg, qw, qb, blkw, blkb, kw, kb, vw, vb,
                          weff, beff, layer, t, sb >> 4, (sb & 15) << 2, scr);
            __syncthreads();                // weff/beff stores drained
            if (t == 0) stw(&sflag[sb], ep);
        }

        // ---- apply (all blocks): wait own batch's 16 weff stripes ----
        {
            if (t < 16) pollw(&sflag[bb * 16 + t], ep);
            __syncthreads();
            float (*wE)[DD] = (float(*)[DD])scr;
            float* beS = scr + DD * DD;
            for (int i = t; i < DD * DD / 2; i += NT) {
                float2 v = ldc2(&weff[(size_t)bb * DD * DD + 2 * i]);
                ((float*)wE)[2 * i] = v.x;
                ((float*)wE)[2 * i + 1] = v.y;
            }
            if (t < DD) beS[t] = ldc(&beff[bb * DD + t]);
            __syncthreads();

            float o[2][4];
            #pragma unroll
            for (int a = 0; a < 2; a++) {
                const int row = r + 16 * a;
                float acc[4];
                #pragma unroll
                for (int b = 0; b < 4; b++) acc[b] = beS[c4 + b];
                for (int d = 0; d < DD; d++) {
                    float hv = sH[row][d];
                    float4 w4 = *(const float4*)&wE[d][c4];
                    acc[0] += hv * w4.x; acc[1] += hv * w4.y;
                    acc[2] += hv * w4.z; acc[3] += hv * w4.w;
                }
                #pragma unroll
                for (int b = 0; b < 4; b++) o[a][b] = gelu_exact(acc[b]);
            }

            if (layer == NLAYER - 1) {
                float pbv = Acc<T>::ld(pb, 0);
                #pragma unroll
                for (int a = 0; a < 2; a++) {
                    float p = 0.f;
                    #pragma unroll
                    for (int b = 0; b < 4; b++) p += o[a][b] * Acc<T>::ld(pw, c4 + b);
                    p += __shfl_xor(p, 1);
                    p += __shfl_xor(p, 2);
                    p += __shfl_xor(p, 4);
                    p += __shfl_xor(p, 8);
                    if ((t & 15) == 0) Acc<T>::st(out, row0 + r + 16 * a, p + pbv);
                }
            } else {
                __syncthreads();            // own-row sH reads done before overwrite
                #pragma unroll
                for (int a = 0; a < 2; a++)
                    *(float4*)&sH[r + 16 * a][c4] =
                        make_float4(o[a][0], o[a][1], o[a][2], o[a][3]);
                __syncthreads();
                accG_part(sH, t, Gpart + (size_t)blk * DD * DD, spart + (size_t)blk * DD);
                __syncthreads();            // partial stores drained
                if (t == 0) stw(&aflag[blk], ep + 1u);
            }
        }
    }
}

__global__ __launch_bounds__(NT) void gno_kernel(
    const void* x, const void* lw, const void* lb,
    const void* blkw, const void* blkb,
    const void* qw, const void* qb, const void* kw, const void* kb,
    const void* vw, const void* vb, const void* pw, const void* pb,
    void* out, float* Gpart, float* spart, float* Gg, float* sg,
    float* weff, float* beff, unsigned* bar)
{
    __shared__ float sH[RPB][SHP];   //  8704 B: resident h rows
    __shared__ float scr[SCRN];      // 21280 B: phase-union scratch
    __shared__ int stot;

    const int blk = blockIdx.x, t = threadIdx.x;

    // dtype detect: every block scans the same 8192 words -> same answer
    if (t == 0) stot = 0;
    __syncthreads();
    int cnt = 0;
    const unsigned int* xw = (const unsigned int*)x;
    for (int i = t; i < 8192; i += NT) {
        unsigned u = xw[i] & 0xFFFFu;
        int e = (u >> 7) & 0xFF;
        cnt += (u == 0u || (e >= 100 && e <= 142)) ? 1 : 0;
    }
    atomicAdd(&stot, cnt);
    __syncthreads();
    const bool isbf = (stot > 4915);

    if (isbf)
        run_net<bf16>(x, lw, lb, blkw, blkb, qw, qb, kw, kb, vw, vb, pw, pb,
                      out, Gpart, spart, Gg, sg, weff, beff, bar, sH, scr, blk, t);
    else
        run_net<float>(x, lw, lb, blkw, blkb, qw, qb, kw, kb, vw, vb, pw, pb,
                       out, Gpart, spart, Gg, sg, weff, beff, bar, sH, scr, blk, t);
}

extern "C" void kernel_launch(void* const* d_in, const int* in_sizes, int n_in,
                              void* d_out, int out_size, void* d_ws, size_t ws_size,
                              hipStream_t stream)
{
    const void* x    = d_in[0];
    const void* lw   = d_in[1];
    const void* lb   = d_in[2];
    const void* blkw = d_in[3];
    const void* blkb = d_in[4];
    const void* qw   = d_in[5];
    const void* qb   = d_in[6];
    const void* kw   = d_in[7];
    const void* kb   = d_in[8];
    const void* vw   = d_in[9];
    const void* vb   = d_in[10];
    const void* pw   = d_in[11];
    const void* pb   = d_in[12];

    unsigned* bar = (unsigned*)d_ws;                      // [512] flag words
    float* Gpart  = (float*)d_ws + 512;                   // [256][64][64] 4 MB
    float* spart  = Gpart + (size_t)NBLK * DD * DD;       // [256][64]
    float* Gg     = spart + (size_t)NBLK * DD;            // [2][64][64]
    float* sg     = Gg + (size_t)NB * DD * DD;            // [2][64]
    float* weff   = sg + (size_t)NB * DD;                 // [2][64][64]
    float* beff   = weff + (size_t)NB * DD * DD;          // [2][64]

    hipMemsetAsync(bar, 0, 512 * sizeof(unsigned), stream);
    gno_kernel<<<NBLK, NT, 0, stream>>>(x, lw, lb, blkw, blkb, qw, qb, kw, kb,
                                        vw, vb, pw, pb, d_out,
                                        Gpart, spart, Gg, sg, weff, beff, bar);
}

// Round 12
// 188.515 us; speedup vs baseline: 2.9455x; 1.0685x over previous
//
#include <hip/hip_runtime.h>
#include <hip/hip_bf16.h>
#include <math.h>

// GNO collapsed: h = lift(x); per layer h = gelu(h@weff + beff) where
//   weff = Wb + c0*Wq@M, beff = bb + c0*bq@M,
//   M = Wk^T G Wv + (Wk^T s) bv^T + bk (s^T Wv) + N bk bv^T, G = h^T h, s = h^T 1.
// Round 12: revert to round-9 proven intrinsics (no inline asm -- round 10/11
// asm path produced NaN). New: (1) per-LAYER Gg/sg/weff/beff buffers so
// consumers use normal CACHED float4 loads (first-touch per XCD per launch;
// producers write sc so data is at the coherence point) -- kills the 4 MB/layer
// serialized weff-broadcast sc reads; (2) Gpart partials staged through LDS and
// stored with wave-linear stc2 (full-line write combining; round 9 showed 2x
// write amplification from strided 8B sc stores).

#define NLAYER 4
#define NB 2
#define NN 4096
#define DD 64
#define RPB 32              // rows per block (8192 rows / 256 blocks)
#define NT 256
#define NBLK 256
#define PPB 128             // G-partial slots per batch
#define C0F (1.0f/32768.0f) // (1/sqrt(64))/4096
#define SHP 68              // padded LDS stride
#define SCRN 5320           // scratch floats

typedef __hip_bfloat16 bf16;
typedef unsigned long long u64t;

__device__ __forceinline__ float b2f(const bf16 v) { return __bfloat162float(v); }

template <typename T> struct Acc;
template <> struct Acc<float> {
    static __device__ __forceinline__ float ld(const void* p, int i) { return ((const float*)p)[i]; }
    static __device__ __forceinline__ void st(void* p, int i, float v) { ((float*)p)[i] = v; }
};
template <> struct Acc<bf16> {
    static __device__ __forceinline__ float ld(const void* p, int i) { return b2f(((const bf16*)p)[i]); }
    static __device__ __forceinline__ void st(void* p, int i, float v) { ((bf16*)p)[i] = __float2bfloat16(v); }
};

__device__ __forceinline__ float gelu_exact(float x) {
    return 0.5f * x * (1.0f + erff(x * 0.70710678118654752f));
}

// ---- device-coherent access helpers (agent scope, relaxed) ----
__device__ __forceinline__ float ldc(const float* p) {
    unsigned u = __hip_atomic_load((const unsigned*)p, __ATOMIC_RELAXED, __HIP_MEMORY_SCOPE_AGENT);
    return __uint_as_float(u);
}
__device__ __forceinline__ void stc(float* p, float v) {
    __hip_atomic_store((unsigned*)p, __float_as_uint(v), __ATOMIC_RELAXED, __HIP_MEMORY_SCOPE_AGENT);
}
__device__ __forceinline__ float2 ldc2(const float* p) {
    u64t v = __hip_atomic_load((const u64t*)p, __ATOMIC_RELAXED, __HIP_MEMORY_SCOPE_AGENT);
    float2 r;
    r.x = __uint_as_float((unsigned)v);
    r.y = __uint_as_float((unsigned)(v >> 32));
    return r;
}
__device__ __forceinline__ void stc2(float* p, float a, float b) {
    u64t v = ((u64t)__float_as_uint(b) << 32) | (u64t)__float_as_uint(a);
    __hip_atomic_store((u64t*)p, v, __ATOMIC_RELAXED, __HIP_MEMORY_SCOPE_AGENT);
}
__device__ __forceinline__ unsigned ldw(unsigned* p) {
    return __hip_atomic_load(p, __ATOMIC_RELAXED, __HIP_MEMORY_SCOPE_AGENT);
}
__device__ __forceinline__ void stw(unsigned* p, unsigned v) {
    __hip_atomic_store(p, v, __ATOMIC_RELAXED, __HIP_MEMORY_SCOPE_AGENT);
}
// Poll epoch word until >= ep. Producer's __syncthreads (vmcnt(0) per wave)
// precedes its flag store, so flag-visibility implies data-visibility.
__device__ __forceinline__ void pollw(unsigned* p, unsigned ep) {
    int guard = 0;
    while (ldw(p) < ep && ++guard < (1 << 17)) __builtin_amdgcn_s_sleep(8);
}

// G-partial + s-partial: compute 4x4 tiles, scatter into LDS (scrG[4160]),
// then wave-linear 8B coherent copy (each store instr covers 512 B contiguous
// -> full-line write combining at the coherence point).
__device__ __forceinline__ void accG_part(const float (*sH)[SHP], float* scrG, int t,
                                          float* __restrict__ Gp, float* __restrict__ sp)
{
    const int tr4 = (t >> 4) << 2, tc4 = (t & 15) << 2;
    float m[4][4];
    #pragma unroll
    for (int a = 0; a < 4; a++)
        #pragma unroll
        for (int b = 0; b < 4; b++) m[a][b] = 0.f;
    #pragma unroll 8
    for (int n = 0; n < RPB; n++) {
        float4 he = *(const float4*)&sH[n][tr4];
        float4 hc = *(const float4*)&sH[n][tc4];
        float ha[4] = {he.x, he.y, he.z, he.w};
        float ca[4] = {hc.x, hc.y, hc.z, hc.w};
        #pragma unroll
        for (int a = 0; a < 4; a++)
            #pragma unroll
            for (int b = 0; b < 4; b++) m[a][b] += ha[a] * ca[b];
    }
    #pragma unroll
    for (int a = 0; a < 4; a++)
        #pragma unroll
        for (int b = 0; b < 4; b++)
            scrG[(tr4 + a) * DD + tc4 + b] = m[a][b];
    if (t < DD) {
        float ss = 0.f;
        #pragma unroll 8
        for (int n = 0; n < RPB; n++) ss += sH[n][t];
        scrG[DD * DD + t] = ss;
    }
    __syncthreads();
    #pragma unroll
    for (int k = 0; k < 8; k++) {
        const int g = 2 * (t + k * NT);
        stc2(&Gp[g], scrG[g], scrG[g + 1]);
    }
    if (t < 32) stc2(&sp[2 * t], scrG[DD * DD + 2 * t], scrG[DD * DD + 2 * t + 1]);
}

// setup: weff/beff column-stripe (4 cols) for (batch bb, stripe S).
// One 17 KB LDS buffer W staged sequentially with G -> Wk -> Wq.
// Gg/sg read with normal cached loads (per-layer unique addresses).
template <typename T>
__device__ void setup_body(const float* Ggl, const float* sgl,
    const void* wq, const void* bq, const void* wb, const void* bbv,
    const void* wk, const void* bk, const void* wv, const void* bv,
    float* wel, float* bel, int layer, int t, int bb, int S, float* scr)
{
    float (*W)[SHP]  = (float(*)[SHP])scr;
    float (*tS)[4]   = (float(*)[4])(scr + 4352);
    float (*mS)[4]   = (float(*)[4])(scr + 4608);
    float (*wvS)[4]  = (float(*)[4])(scr + 4864);
    float* sS  = scr + 5120;
    float* bkS = scr + 5184;
    float* bqS = scr + 5248;
    float* suS = scr + 5312;
    float* bvS = scr + 5316;

    const int wOff = layer * DD * DD, bOff = layer * DD;
    {   // stage G via cached float4 loads
        const float4* gb4 = (const float4*)(Ggl + (size_t)bb * DD * DD);
        for (int i = t; i < DD * DD / 4; i += NT) {
            float4 v = gb4[i];
            const int idx = 4 * i;
            *(float4*)&W[idx >> 6][idx & 63] = v;
        }
    }
    for (int i = t; i < DD * 4; i += NT)
        wvS[i >> 2][i & 3] = Acc<T>::ld(wv, wOff + (i >> 2) * DD + S + (i & 3));
    if (t < DD) {
        sS[t]  = sgl[bb * DD + t];          // cached
        bkS[t] = Acc<T>::ld(bk, bOff + t);
        bqS[t] = Acc<T>::ld(bq, bOff + t);
    }
    if (t < 4) bvS[t] = Acc<T>::ld(bv, bOff + S + t);
    __syncthreads();

    const int r = t >> 2, j = t & 3;
    // P1: T'[:,S] = G.Wv[:,S] + s bv^T  (W = G, symmetric -> row read)
    {
        float a0 = 0.f, a1 = 0.f, a2 = 0.f, a3 = 0.f;
        for (int e = 0; e < DD; e += 4) {
            a0 += W[r][e]     * wvS[e][j];
            a1 += W[r][e + 1] * wvS[e + 1][j];
            a2 += W[r][e + 2] * wvS[e + 2][j];
            a3 += W[r][e + 3] * wvS[e + 3][j];
        }
        tS[r][j] = (a0 + a1) + (a2 + a3) + sS[r] * bvS[j];
        if (t < 4) {
            float u0 = 0.f;
            for (int d = 0; d < DD; d++) u0 += sS[d] * wvS[d][t];
            suS[t] = u0 + (float)NN * bvS[t];
        }
    }
    __syncthreads();
    for (int i = t; i < DD * DD; i += NT) W[i >> 6][i & 63] = Acc<T>::ld(wk, wOff + i);
    __syncthreads();
    // P2: M[:,S] = Wk^T.T' + bk su^T   (W = Wk)
    {
        float a0 = 0.f, a1 = 0.f, a2 = 0.f, a3 = 0.f;
        for (int d = 0; d < DD; d += 4) {
            a0 += W[d][r]     * tS[d][j];
            a1 += W[d + 1][r] * tS[d + 1][j];
            a2 += W[d + 2][r] * tS[d + 2][j];
            a3 += W[d + 3][r] * tS[d + 3][j];
        }
        mS[r][j] = (a0 + a1) + (a2 + a3) + bkS[r] * suS[j];
    }
    __syncthreads();
    for (int i = t; i < DD * DD; i += NT) W[i >> 6][i & 63] = Acc<T>::ld(wq, wOff + i);
    __syncthreads();
    // P3: weff[:,S] = Wb[:,S] + C0*Wq.M[:,S]; beff[S] = bb[S] + C0*bq.M[:,S]
    {
        float a0 = 0.f, a1 = 0.f, a2 = 0.f, a3 = 0.f;
        for (int e = 0; e < DD; e += 4) {
            a0 += W[r][e]     * mS[e][j];
            a1 += W[r][e + 1] * mS[e + 1][j];
            a2 += W[r][e + 2] * mS[e + 2][j];
            a3 += W[r][e + 3] * mS[e + 3][j];
        }
        stc(&wel[bb * DD * DD + r * DD + S + j],
            Acc<T>::ld(wb, wOff + r * DD + S + j) + C0F * ((a0 + a1) + (a2 + a3)));
        if (t < 4) {
            float u = 0.f;
            for (int e = 0; e < DD; e++) u += bqS[e] * mS[e][t];
            stc(&bel[bb * DD + S + t], Acc<T>::ld(bbv, bOff + S + t) + C0F * u);
        }
    }
}

template <typename T>
__device__ void run_net(
    const void* x, const void* lw, const void* lb,
    const void* blkw, const void* blkb,
    const void* qw, const void* qb, const void* kw, const void* kb,
    const void* vw, const void* vb, const void* pw, const void* pb,
    void* out, float* Gpart, float* spart, float* Gg, float* sg,
    float* weff, float* beff, unsigned* bar,
    float (*sH)[SHP], float* scr, int blk, int t)
{
    unsigned* aflag = bar;            // [256] apply/lift done epochs
    unsigned* cflag = bar + 256;      // [130] combine done epochs
    unsigned* sflag = bar + 392;      // [32]  setup done epochs

    const int row0 = blk * RPB;
    const int bb = row0 >> 12;
    const int r = t >> 4, c4 = (t & 15) << 2;

    // ---- lift: h rows into resident LDS; write G0/s0 partials ----
    #pragma unroll
    for (int a = 0; a < 2; a++) {
        const int row = r + 16 * a, gr = row0 + row;
        float x0 = Acc<T>::ld(x, gr * 3 + 0);
        float x1 = Acc<T>::ld(x, gr * 3 + 1);
        float x2 = Acc<T>::ld(x, gr * 3 + 2);
        float o[4];
        #pragma unroll
        for (int b = 0; b < 4; b++) {
            int c = c4 + b;
            o[b] = Acc<T>::ld(lb, c) + x0 * Acc<T>::ld(lw, c)
                 + x1 * Acc<T>::ld(lw, DD + c) + x2 * Acc<T>::ld(lw, 2 * DD + c);
        }
        *(float4*)&sH[row][c4] = make_float4(o[0], o[1], o[2], o[3]);
    }
    __syncthreads();
    accG_part(sH, scr, t, Gpart + (size_t)blk * DD * DD, spart + (size_t)blk * DD);
    __syncthreads();                        // all partial stores drained (vmcnt 0)
    if (t == 0) stw(&aflag[blk], 1u);

    for (int layer = 0; layer < NLAYER; layer++) {
        const unsigned ep = (unsigned)(layer + 1);
        float* Ggl = Gg + (size_t)layer * NB * DD * DD;
        float* sgl = sg + (size_t)layer * NB * DD;
        float* wel = weff + (size_t)layer * NB * DD * DD;
        float* bel = beff + (size_t)layer * NB * DD;

        // ---- combine (blocks 0..129): wait all 256 partials, reduce ----
        if (blk < 2 * DD + NB) {
            pollw(&aflag[t], ep);           // thread t waits block t's partial
            __syncthreads();
            float (*red)[DD] = (float(*)[DD])scr;   // [8][64]
            const int cp = t & 31, kg = t >> 5;     // 32 col-pairs x 8 k-groups
            if (blk < 2 * DD) {
                const int batch = blk >> 6, grow = blk & 63;
                const float* base = Gpart + ((size_t)(batch * PPB) << 12) + grow * DD + 2 * cp;
                float ax = 0.f, ay = 0.f;
                #pragma unroll 4
                for (int k = 0; k < 16; k++) {
                    float2 v = ldc2(&base[(size_t)(kg * 16 + k) << 12]);
                    ax += v.x; ay += v.y;
                }
                red[kg][2 * cp] = ax; red[kg][2 * cp + 1] = ay;
                __syncthreads();
                if (t < 32) {
                    float s0 = 0.f, s1 = 0.f;
                    #pragma unroll
                    for (int g = 0; g < 8; g++) { s0 += red[g][2 * t]; s1 += red[g][2 * t + 1]; }
                    stc2(&Ggl[batch * DD * DD + grow * DD + 2 * t], s0, s1);
                }
            } else {
                const int batch = blk - 2 * DD;
                float ax = 0.f, ay = 0.f;
                #pragma unroll 4
                for (int k = 0; k < 16; k++) {
                    float2 v = ldc2(&spart[(size_t)(batch * PPB + kg * 16 + k) * DD + 2 * cp]);
                    ax += v.x; ay += v.y;
                }
                red[kg][2 * cp] = ax; red[kg][2 * cp + 1] = ay;
                __syncthreads();
                if (t < 32) {
                    float s0 = 0.f, s1 = 0.f;
                    #pragma unroll
                    for (int g = 0; g < 8; g++) { s0 += red[g][2 * t]; s1 += red[g][2 * t + 1]; }
                    stc2(&sgl[batch * DD + 2 * t], s0, s1);
                }
            }
            __syncthreads();                // Gg/sg stores drained
            if (t == 0) stw(&cflag[blk], ep);
        }

        // ---- setup (blocks 130..161): wait 130 combine flags, build weff ----
        if (blk >= 2 * DD + NB && blk < 2 * DD + NB + NB * 16) {
            const int sb = blk - (2 * DD + NB);
            if (t < 2 * DD + NB) pollw(&cflag[t], ep);
            __syncthreads();
            setup_body<T>(Ggl, sgl, qw, qb, blkw, blkb, kw, kb, vw, vb,
                          wel, bel, layer, t, sb >> 4, (sb & 15) << 2, scr);
            __syncthreads();                // weff/beff stores drained
            if (t == 0) stw(&sflag[sb], ep);
        }

        // ---- apply (all blocks): wait own batch's 16 weff stripes ----
        {
            if (t < 16) pollw(&sflag[bb * 16 + t], ep);
            __syncthreads();
            float (*wE)[DD] = (float(*)[DD])scr;
            float* beS = scr + DD * DD;
            {   // cached float4 staging (per-layer unique addresses)
                const float4* ws4 = (const float4*)(wel + (size_t)bb * DD * DD);
                float4* wd4 = (float4*)&wE[0][0];
                for (int i = t; i < DD * DD / 4; i += NT) wd4[i] = ws4[i];
            }
            if (t < DD) beS[t] = bel[bb * DD + t];   // cached
            __syncthreads();

            float o[2][4];
            #pragma unroll
            for (int a = 0; a < 2; a++) {
                const int row = r + 16 * a;
                float acc[4];
                #pragma unroll
                for (int b = 0; b < 4; b++) acc[b] = beS[c4 + b];
                for (int d = 0; d < DD; d++) {
                    float hv = sH[row][d];
                    float4 w4 = *(const float4*)&wE[d][c4];
                    acc[0] += hv * w4.x; acc[1] += hv * w4.y;
                    acc[2] += hv * w4.z; acc[3] += hv * w4.w;
                }
                #pragma unroll
                for (int b = 0; b < 4; b++) o[a][b] = gelu_exact(acc[b]);
            }

            if (layer == NLAYER - 1) {
                float pbv = Acc<T>::ld(pb, 0);
                #pragma unroll
                for (int a = 0; a < 2; a++) {
                    float p = 0.f;
                    #pragma unroll
                    for (int b = 0; b < 4; b++) p += o[a][b] * Acc<T>::ld(pw, c4 + b);
                    p += __shfl_xor(p, 1);
                    p += __shfl_xor(p, 2);
                    p += __shfl_xor(p, 4);
                    p += __shfl_xor(p, 8);
                    if ((t & 15) == 0) Acc<T>::st(out, row0 + r + 16 * a, p + pbv);
                }
            } else {
                __syncthreads();            // wE/beS/sH reads done before overwrite
                #pragma unroll
                for (int a = 0; a < 2; a++)
                    *(float4*)&sH[r + 16 * a][c4] =
                        make_float4(o[a][0], o[a][1], o[a][2], o[a][3]);
                __syncthreads();
                accG_part(sH, scr, t, Gpart + (size_t)blk * DD * DD, spart + (size_t)blk * DD);
                __syncthreads();            // partial stores drained
                if (t == 0) stw(&aflag[blk], ep + 1u);
            }
        }
    }
}

__global__ __launch_bounds__(NT) void gno_kernel(
    const void* x, const void* lw, const void* lb,
    const void* blkw, const void* blkb,
    const void* qw, const void* qb, const void* kw, const void* kb,
    const void* vw, const void* vb, const void* pw, const void* pb,
    void* out, float* Gpart, float* spart, float* Gg, float* sg,
    float* weff, float* beff, unsigned* bar)
{
    __shared__ alignas(16) float sH[RPB][SHP];   //  8704 B: resident h rows
    __shared__ alignas(16) float scr[SCRN];      // 21280 B: phase-union scratch
    __shared__ int stot;

    const int blk = blockIdx.x, t = threadIdx.x;

    // dtype detect: every block scans the same 8192 words -> same answer
    if (t == 0) stot = 0;
    __syncthreads();
    int cnt = 0;
    const unsigned int* xw = (const unsigned int*)x;
    for (int i = t; i < 8192; i += NT) {
        unsigned u = xw[i] & 0xFFFFu;
        int e = (u >> 7) & 0xFF;
        cnt += (u == 0u || (e >= 100 && e <= 142)) ? 1 : 0;
    }
    atomicAdd(&stot, cnt);
    __syncthreads();
    const bool isbf = (stot > 4915);

    if (isbf)
        run_net<bf16>(x, lw, lb, blkw, blkb, qw, qb, kw, kb, vw, vb, pw, pb,
                      out, Gpart, spart, Gg, sg, weff, beff, bar, sH, scr, blk, t);
    else
        run_net<float>(x, lw, lb, blkw, blkb, qw, qb, kw, kb, vw, vb, pw, pb,
                       out, Gpart, spart, Gg, sg, weff, beff, bar, sH, scr, blk, t);
}

extern "C" void kernel_launch(void* const* d_in, const int* in_sizes, int n_in,
                              void* d_out, int out_size, void* d_ws, size_t ws_size,
                              hipStream_t stream)
{
    const void* x    = d_in[0];
    const void* lw   = d_in[1];
    const void* lb   = d_in[2];
    const void* blkw = d_in[3];
    const void* blkb = d_in[4];
    const void* qw   = d_in[5];
    const void* qb   = d_in[6];
    const void* kw   = d_in[7];
    const void* kb   = d_in[8];
    const void* vw   = d_in[9];
    const void* vb   = d_in[10];
    const void* pw   = d_in[11];
    const void* pb   = d_in[12];

    unsigned* bar = (unsigned*)d_ws;                      // [512] flag words
    float* Gpart  = (float*)d_ws + 512;                   // [256][64][64] 4 MB
    float* spart  = Gpart + (size_t)NBLK * DD * DD;       // [256][64]
    float* Gg     = spart + (size_t)NBLK * DD;            // [4][2][64][64] per-layer
    float* sg     = Gg + (size_t)NLAYER * NB * DD * DD;   // [4][2][64]
    float* weff   = sg + (size_t)NLAYER * NB * DD;        // [4][2][64][64] per-layer
    float* beff   = weff + (size_t)NLAYER * NB * DD * DD; // [4][2][64]

    hipMemsetAsync(bar, 0, 512 * sizeof(unsigned), stream);
    gno_kernel<<<NBLK, NT, 0, stream>>>(x, lw, lb, blkw, blkb, qw, qb, kw, kb,
                                        vw, vb, pw, pb, d_out,
                                        Gpart, spart, Gg, sg, weff, beff, bar);
}